// Round 2
// baseline (653.055 us; speedup 1.0000x reference)
//
#include <hip/hip_runtime.h>
#include <hip/hip_bf16.h>

#define NSP 4096
#define BEPS 1e-5f

// ---------------- Kernel 1: qkv = BN(conv1x1(x)) ; split into q,k,v ----------------
// x: (B,256,4096) f32 ; w: (512,256) f32 ; out q,k (bh,32,4096) f32, v (bh,64,4096) f32
__global__ __launch_bounds__(256) void qkv_kernel(
    const float* __restrict__ x,
    const float* __restrict__ w,
    const float* __restrict__ gg,
    const float* __restrict__ bb,
    const float* __restrict__ mm,
    const float* __restrict__ vv,
    float* __restrict__ qb, float* __restrict__ kb, float* __restrict__ vb)
{
  const int n0  = blockIdx.x * 64;
  const int co0 = blockIdx.y * 64;
  const int b   = blockIdx.z;
  const int t   = threadIdx.x;
  const int tx  = t & 15, ty = t >> 4;
  __shared__ __align__(16) float xs[32][68];   // [k][n]
  __shared__ float wst[32][69];                // [k][co], pad 69 -> conflict-free transposed writes
  float acc[4][4] = {};
  for (int k0 = 0; k0 < 256; k0 += 32) {
    {
      int nl = t & 63, kk = t >> 6;
      #pragma unroll
      for (int r = 0; r < 8; ++r, kk += 4)
        xs[kk][nl] = x[((size_t)(b * 256 + k0 + kk)) * NSP + n0 + nl];
      int kk2 = t & 31, co = t >> 5;
      #pragma unroll
      for (int r = 0; r < 8; ++r, co += 8)
        wst[kk2][co] = w[(size_t)(co0 + co) * 256 + k0 + kk2];
    }
    __syncthreads();
    #pragma unroll 8
    for (int kk = 0; kk < 32; ++kk) {
      const float4 xv = *reinterpret_cast<const float4*>(&xs[kk][tx * 4]);
      const float xa[4] = {xv.x, xv.y, xv.z, xv.w};
      float wr[4];
      #pragma unroll
      for (int cc = 0; cc < 4; ++cc) wr[cc] = wst[kk][ty * 4 + cc];
      #pragma unroll
      for (int cc = 0; cc < 4; ++cc)
        #pragma unroll
        for (int nn = 0; nn < 4; ++nn) acc[cc][nn] += wr[cc] * xa[nn];
    }
    __syncthreads();
  }
  #pragma unroll
  for (int cc = 0; cc < 4; ++cc) {
    const int c  = co0 + ty * 4 + cc;
    const float sc = gg[c] * rsqrtf(vv[c] + BEPS);
    const float bi = bb[c] - mm[c] * sc;
    float4 ov;
    ov.x = acc[cc][0] * sc + bi; ov.y = acc[cc][1] * sc + bi;
    ov.z = acc[cc][2] * sc + bi; ov.w = acc[cc][3] * sc + bi;
    const int head = c >> 7, r = c & 127;
    const int bh = b * 4 + head;
    float* dst;
    if (r < 32)      dst = qb + ((size_t)(bh * 32 + r)) * NSP;
    else if (r < 64) dst = kb + ((size_t)(bh * 32 + (r - 32))) * NSP;
    else             dst = vb + ((size_t)(bh * 64 + (r - 64))) * NSP;
    *reinterpret_cast<float4*>(dst + n0 + tx * 4) = ov;
  }
}

// ---------------- Kernel 2: flash attention per (b,h) ----------------
// q,k: (bh,32,N) ; v: (bh,64,N) ; y out: (b,256,N) with c = h*64+d
__global__ __launch_bounds__(256) void attn_kernel(
    const float* __restrict__ qb, const float* __restrict__ kb,
    const float* __restrict__ vb, float* __restrict__ y)
{
  const int i0 = blockIdx.x * 64;
  const int bh = blockIdx.y;
  const int t  = threadIdx.x;
  const int tx = t & 15, ty = t >> 4;
  __shared__ __align__(16) float qs[32][68];   // [d][i]
  __shared__ __align__(16) float ks[32][68];   // [d][j]
  __shared__ float vs[64][69];                 // [j][d] transposed, pad 69
  __shared__ __align__(16) float ps[64][68];   // [j][i]
  __shared__ float mrow[64], lrow[64], arow[64];
  const float* q = qb + (size_t)bh * 32 * NSP;
  const float* k = kb + (size_t)bh * 32 * NSP;
  const float* v = vb + (size_t)bh * 64 * NSP;
  {
    int il = t & 63, d = t >> 6;
    #pragma unroll
    for (int r = 0; r < 8; ++r, d += 4)
      qs[d][il] = q[(size_t)d * NSP + i0 + il];
  }
  if (t < 64) { mrow[t] = -1e30f; lrow[t] = 0.f; }
  float o[4][4] = {};
  const float scale = 0.17677669529663689f;  // 32^-0.5
  __syncthreads();
  for (int j0 = 0; j0 < NSP; j0 += 64) {
    {
      int jl = t & 63, d = t >> 6;
      #pragma unroll
      for (int r = 0; r < 8; ++r, d += 4) ks[d][jl] = k[(size_t)d * NSP + j0 + jl];
      d = t >> 6;
      #pragma unroll
      for (int r = 0; r < 16; ++r, d += 4) vs[jl][d] = v[(size_t)d * NSP + j0 + jl];
    }
    __syncthreads();
    // S = scale * q^T k ; mapping: i = ty*4+ii, j = tx*4+jj
    float s[4][4] = {};
    #pragma unroll 8
    for (int kk = 0; kk < 32; ++kk) {
      const float4 qv = *reinterpret_cast<const float4*>(&qs[kk][ty * 4]);
      const float4 kv = *reinterpret_cast<const float4*>(&ks[kk][tx * 4]);
      const float qa[4] = {qv.x, qv.y, qv.z, qv.w};
      const float ka[4] = {kv.x, kv.y, kv.z, kv.w};
      #pragma unroll
      for (int ii = 0; ii < 4; ++ii)
        #pragma unroll
        for (int jj = 0; jj < 4; ++jj) s[ii][jj] += qa[ii] * ka[jj];
    }
    // online softmax; 16 lanes (same ty) share each row -> shfl reduce within 16-lane group
    #pragma unroll
    for (int ii = 0; ii < 4; ++ii) {
      #pragma unroll
      for (int jj = 0; jj < 4; ++jj) s[ii][jj] *= scale;
      float tm = fmaxf(fmaxf(s[ii][0], s[ii][1]), fmaxf(s[ii][2], s[ii][3]));
      tm = fmaxf(tm, __shfl_xor(tm, 1));
      tm = fmaxf(tm, __shfl_xor(tm, 2));
      tm = fmaxf(tm, __shfl_xor(tm, 4));
      tm = fmaxf(tm, __shfl_xor(tm, 8));
      const int irow = ty * 4 + ii;
      const float mo = mrow[irow];
      const float mn = fmaxf(mo, tm);
      const float al = __expf(mo - mn);
      float rs = 0.f;
      #pragma unroll
      for (int jj = 0; jj < 4; ++jj) {
        float p = __expf(s[ii][jj] - mn);
        s[ii][jj] = p; rs += p;
      }
      rs += __shfl_xor(rs, 1); rs += __shfl_xor(rs, 2);
      rs += __shfl_xor(rs, 4); rs += __shfl_xor(rs, 8);
      if (tx == 0) { mrow[irow] = mn; lrow[irow] = lrow[irow] * al + rs; arow[irow] = al; }
    }
    // stash P transposed: ps[j][i]
    #pragma unroll
    for (int jj = 0; jj < 4; ++jj) {
      float4 pv; pv.x = s[0][jj]; pv.y = s[1][jj]; pv.z = s[2][jj]; pv.w = s[3][jj];
      *reinterpret_cast<float4*>(&ps[tx * 4 + jj][ty * 4]) = pv;
    }
    __syncthreads();
    // PV: remap: i = tx*4+ii, d = ty*4+dd
    float al2[4];
    #pragma unroll
    for (int ii = 0; ii < 4; ++ii) al2[ii] = arow[tx * 4 + ii];
    #pragma unroll
    for (int dd = 0; dd < 4; ++dd)
      #pragma unroll
      for (int ii = 0; ii < 4; ++ii) o[dd][ii] *= al2[ii];
    #pragma unroll 4
    for (int j = 0; j < 64; ++j) {
      const float4 pv = *reinterpret_cast<const float4*>(&ps[j][tx * 4]);
      const float pa[4] = {pv.x, pv.y, pv.z, pv.w};
      float vr[4];
      #pragma unroll
      for (int dd = 0; dd < 4; ++dd) vr[dd] = vs[j][ty * 4 + dd];
      #pragma unroll
      for (int dd = 0; dd < 4; ++dd)
        #pragma unroll
        for (int ii = 0; ii < 4; ++ii) o[dd][ii] += vr[dd] * pa[ii];
    }
    __syncthreads();
  }
  float li[4];
  #pragma unroll
  for (int ii = 0; ii < 4; ++ii) li[ii] = 1.0f / lrow[tx * 4 + ii];
  const int b = bh >> 2, h = bh & 3;
  #pragma unroll
  for (int dd = 0; dd < 4; ++dd) {
    const int c = h * 64 + ty * 4 + dd;
    float4 ov;
    ov.x = o[dd][0] * li[0]; ov.y = o[dd][1] * li[1];
    ov.z = o[dd][2] * li[2]; ov.w = o[dd][3] * li[3];
    *reinterpret_cast<float4*>(y + ((size_t)(b * 256 + c)) * NSP + i0 + tx * 4) = ov;
  }
}

// ---------------- Kernel 3: y += BN(depthwise3x3(v)) ----------------
__global__ __launch_bounds__(256) void pe_kernel(
    const float* __restrict__ vb,                  // (B,256,64,64) == v workspace layout
    const float* __restrict__ pw,
    const float* __restrict__ gg,
    const float* __restrict__ bb,
    const float* __restrict__ mm,
    const float* __restrict__ vv,
    float* __restrict__ y)
{
  const int bc = blockIdx.x;        // b*256 + c
  const int c  = bc & 255;
  const float* vp = vb + (size_t)bc * 4096;
  float w9[9];
  #pragma unroll
  for (int i = 0; i < 9; ++i) w9[i] = pw[c * 9 + i];
  const float sc = gg[c] * rsqrtf(vv[c] + BEPS);
  const float bi = bb[c] - mm[c] * sc;
  for (int p = threadIdx.x; p < 4096; p += 256) {
    const int py = p >> 6, px = p & 63;
    float sum = 0.f;
    #pragma unroll
    for (int ky = -1; ky <= 1; ++ky) {
      const int yy = py + ky;
      if (yy < 0 || yy > 63) continue;
      #pragma unroll
      for (int kx = -1; kx <= 1; ++kx) {
        const int xx = px + kx;
        if (xx < 0 || xx > 63) continue;
        sum += vp[yy * 64 + xx] * w9[(ky + 1) * 3 + (kx + 1)];
      }
    }
    y[(size_t)bc * 4096 + p] += sum * sc + bi;
  }
}

// ---------------- Kernel 4: out = BN(conv1x1(y)) -> f32 ----------------
__global__ __launch_bounds__(256) void proj_kernel(
    const float* __restrict__ yin,
    const float* __restrict__ w,
    const float* __restrict__ gg,
    const float* __restrict__ bb,
    const float* __restrict__ mm,
    const float* __restrict__ vv,
    float* __restrict__ out)
{
  const int n0  = blockIdx.x * 64;
  const int co0 = blockIdx.y * 64;
  const int b   = blockIdx.z;
  const int t   = threadIdx.x;
  const int tx  = t & 15, ty = t >> 4;
  __shared__ __align__(16) float xs[32][68];
  __shared__ float wst[32][69];
  float acc[4][4] = {};
  for (int k0 = 0; k0 < 256; k0 += 32) {
    {
      int nl = t & 63, kk = t >> 6;
      #pragma unroll
      for (int r = 0; r < 8; ++r, kk += 4)
        xs[kk][nl] = yin[((size_t)(b * 256 + k0 + kk)) * NSP + n0 + nl];
      int kk2 = t & 31, co = t >> 5;
      #pragma unroll
      for (int r = 0; r < 8; ++r, co += 8)
        wst[kk2][co] = w[(size_t)(co0 + co) * 256 + k0 + kk2];
    }
    __syncthreads();
    #pragma unroll 8
    for (int kk = 0; kk < 32; ++kk) {
      const float4 xv = *reinterpret_cast<const float4*>(&xs[kk][tx * 4]);
      const float xa[4] = {xv.x, xv.y, xv.z, xv.w};
      float wr[4];
      #pragma unroll
      for (int cc = 0; cc < 4; ++cc) wr[cc] = wst[kk][ty * 4 + cc];
      #pragma unroll
      for (int cc = 0; cc < 4; ++cc)
        #pragma unroll
        for (int nn = 0; nn < 4; ++nn) acc[cc][nn] += wr[cc] * xa[nn];
    }
    __syncthreads();
  }
  #pragma unroll
  for (int cc = 0; cc < 4; ++cc) {
    const int c  = co0 + ty * 4 + cc;
    const float sc = gg[c] * rsqrtf(vv[c] + BEPS);
    const float bi = bb[c] - mm[c] * sc;
    float4 ov;
    ov.x = acc[cc][0] * sc + bi; ov.y = acc[cc][1] * sc + bi;
    ov.z = acc[cc][2] * sc + bi; ov.w = acc[cc][3] * sc + bi;
    *reinterpret_cast<float4*>(out + ((size_t)(b * 256 + c)) * NSP + n0 + tx * 4) = ov;
  }
}

extern "C" void kernel_launch(void* const* d_in, const int* in_sizes, int n_in,
                              void* d_out, int out_size, void* d_ws, size_t ws_size,
                              hipStream_t stream)
{
  const float* x      = (const float*)d_in[0];
  const float* qkv_w  = (const float*)d_in[1];
  const float* qkv_g  = (const float*)d_in[2];
  const float* qkv_b  = (const float*)d_in[3];
  const float* qkv_m  = (const float*)d_in[4];
  const float* qkv_v  = (const float*)d_in[5];
  const float* proj_w = (const float*)d_in[6];
  const float* proj_g = (const float*)d_in[7];
  const float* proj_b = (const float*)d_in[8];
  const float* proj_m = (const float*)d_in[9];
  const float* proj_v = (const float*)d_in[10];
  const float* pe_w   = (const float*)d_in[11];
  const float* pe_g   = (const float*)d_in[12];
  const float* pe_b   = (const float*)d_in[13];
  const float* pe_m   = (const float*)d_in[14];
  const float* pe_v   = (const float*)d_in[15];
  float* out = (float*)d_out;

  float* qb = (float*)d_ws;                        // 8 heads * 32 * 4096 = 1M floats
  float* kb = qb + (size_t)8 * 32 * NSP;           // 1M floats
  float* vb = kb + (size_t)8 * 32 * NSP;           // 2M floats
  float* yy = vb + (size_t)8 * 64 * NSP;           // 2M floats  (total 24 MB)

  qkv_kernel<<<dim3(64, 8, 2), 256, 0, stream>>>(x, qkv_w, qkv_g, qkv_b, qkv_m, qkv_v,
                                                 qb, kb, vb);
  attn_kernel<<<dim3(64, 8), 256, 0, stream>>>(qb, kb, vb, yy);
  pe_kernel<<<dim3(512), 256, 0, stream>>>(vb, pe_w, pe_g, pe_b, pe_m, pe_v, yy);
  proj_kernel<<<dim3(64, 4, 2), 256, 0, stream>>>(yy, proj_w, proj_g, proj_b, proj_m, proj_v,
                                                  out);
}

// Round 3
// 360.328 us; speedup vs baseline: 1.8124x; 1.8124x over previous
//
#include <hip/hip_runtime.h>
#include <hip/hip_bf16.h>

#define NSP 4096
#define BEPS 1e-5f

using short8  = __attribute__((ext_vector_type(8))) short;
using f32x4   = __attribute__((ext_vector_type(4))) float;
using ushort4v= __attribute__((ext_vector_type(4))) unsigned short;

// float -> bf16 bits, round-nearest-even
__device__ __forceinline__ unsigned short f2b(float x) {
  unsigned u = __float_as_uint(x);
  u += 0x7fffu + ((u >> 16) & 1u);
  return (unsigned short)(u >> 16);
}
__device__ __forceinline__ float b2f(unsigned short u) {
  return __uint_as_float(((unsigned)u) << 16);
}

// ---------------- Kernel 1: qkv = BN(conv1x1(x)) ; split into q,k,v (bf16 outs) --------
// q,k: (bh, 4096 i, 32 d) bf16 (i-major)   v: (bh, 64 d, 4096 j) bf16 (d-major)
__global__ __launch_bounds__(256) void qkv_kernel(
    const float* __restrict__ x,
    const float* __restrict__ w,
    const float* __restrict__ gg,
    const float* __restrict__ bb,
    const float* __restrict__ mm,
    const float* __restrict__ vv,
    unsigned short* __restrict__ qb, unsigned short* __restrict__ kb,
    unsigned short* __restrict__ vb)
{
  const int n0  = blockIdx.x * 64;
  const int co0 = blockIdx.y * 64;
  const int b   = blockIdx.z;
  const int t   = threadIdx.x;
  const int tx  = t & 15, ty = t >> 4;
  __shared__ __align__(16) float xs[32][68];   // [k][n]
  __shared__ float wst[32][69];                // [k][co]
  float acc[4][4] = {};
  for (int k0 = 0; k0 < 256; k0 += 32) {
    {
      int nl = t & 63, kk = t >> 6;
      #pragma unroll
      for (int r = 0; r < 8; ++r, kk += 4)
        xs[kk][nl] = x[((size_t)(b * 256 + k0 + kk)) * NSP + n0 + nl];
      int kk2 = t & 31, co = t >> 5;
      #pragma unroll
      for (int r = 0; r < 8; ++r, co += 8)
        wst[kk2][co] = w[(size_t)(co0 + co) * 256 + k0 + kk2];
    }
    __syncthreads();
    #pragma unroll 8
    for (int kk = 0; kk < 32; ++kk) {
      const float4 xv = *reinterpret_cast<const float4*>(&xs[kk][tx * 4]);
      const float xa[4] = {xv.x, xv.y, xv.z, xv.w};
      float wr[4];
      #pragma unroll
      for (int cc = 0; cc < 4; ++cc) wr[cc] = wst[kk][ty * 4 + cc];
      #pragma unroll
      for (int cc = 0; cc < 4; ++cc)
        #pragma unroll
        for (int nn = 0; nn < 4; ++nn) acc[cc][nn] += wr[cc] * xa[nn];
    }
    __syncthreads();
  }
  #pragma unroll
  for (int cc = 0; cc < 4; ++cc) {
    const int c  = co0 + ty * 4 + cc;
    const float sc = gg[c] * rsqrtf(vv[c] + BEPS);
    const float bi = bb[c] - mm[c] * sc;
    float o[4];
    #pragma unroll
    for (int nn = 0; nn < 4; ++nn) o[nn] = acc[cc][nn] * sc + bi;
    const int head = c >> 7, r = c & 127;
    const int bh = b * 4 + head;
    const int i = n0 + tx * 4;
    if (r < 64) {  // q or k: (bh, i, d) i-major
      unsigned short* dst = (r < 32) ? qb : kb;
      const int d = r & 31;
      size_t base = ((size_t)bh * NSP + i) * 32 + d;
      dst[base]      = f2b(o[0]);
      dst[base + 32] = f2b(o[1]);
      dst[base + 64] = f2b(o[2]);
      dst[base + 96] = f2b(o[3]);
    } else {       // v: (bh, d, j) d-major
      const int d = r - 64;
      ushort4v pk = { f2b(o[0]), f2b(o[1]), f2b(o[2]), f2b(o[3]) };
      *reinterpret_cast<ushort4v*>(vb + ((size_t)(bh * 64 + d)) * NSP + i) = pk;
    }
  }
}

// ---------------- Kernel 2: MFMA flash attention per (b,h) ----------------
// q,k: (bh,4096,32) bf16 ; v: (bh,64,4096) bf16 ; y out: (b,256,4096) f32
__global__ __launch_bounds__(256) void attn_kernel(
    const unsigned short* __restrict__ qb, const unsigned short* __restrict__ kb,
    const unsigned short* __restrict__ vb, float* __restrict__ y)
{
  const int i0 = blockIdx.x * 64;
  const int bh = blockIdx.y;
  const int t  = threadIdx.x;
  const int lane = t & 63, wave = t >> 6;
  const int m16 = lane & 15, quad = lane >> 4;
  __shared__ __align__(16) short qs[64][40];   // [i][d] pad 40 (80B rows, 16B-aligned)
  __shared__ __align__(16) short ks[64][40];   // [j][d]
  __shared__ __align__(16) short vs[64][72];   // [d][j] pad 72 (144B rows)
  __shared__ __align__(16) short ps[64][72];   // [i][j] bf16 P, wave-private rows

  const int srow = t >> 2, schunk = t & 3;
  {  // stage Q once: 64 rows x 32 bf16
    const unsigned short* qp = qb + ((size_t)bh * NSP + i0) * 32;
    *reinterpret_cast<float4*>(&qs[srow][schunk * 8]) =
        *reinterpret_cast<const float4*>(qp + srow * 32 + schunk * 8);
  }
  __syncthreads();
  const short8 qfrag = *reinterpret_cast<const short8*>(&qs[wave * 16 + m16][quad * 8]);

  float mreg[4] = {-1e30f, -1e30f, -1e30f, -1e30f};
  float lreg[4] = {0.f, 0.f, 0.f, 0.f};
  f32x4 oacc[4] = {};
  const float scale = 0.17677669529663689f;  // 32^-0.5

  for (int j0 = 0; j0 < NSP; j0 += 64) {
    __syncthreads();  // prev-iter PV reads of ks/vs done before restaging
    {
      const unsigned short* kp = kb + ((size_t)bh * NSP + j0) * 32;
      *reinterpret_cast<float4*>(&ks[srow][schunk * 8]) =
          *reinterpret_cast<const float4*>(kp + srow * 32 + schunk * 8);
      const unsigned short* vp = vb + (size_t)bh * 64 * NSP + j0;
      *reinterpret_cast<float4*>(&vs[srow][schunk * 16]) =
          *reinterpret_cast<const float4*>(vp + (size_t)srow * NSP + schunk * 16);
      *reinterpret_cast<float4*>(&vs[srow][schunk * 16 + 8]) =
          *reinterpret_cast<const float4*>(vp + (size_t)srow * NSP + schunk * 16 + 8);
    }
    __syncthreads();

    // S tile: wave's 16 i's x 64 j's. A=Q, B=K.
    f32x4 sacc[4];
    #pragma unroll
    for (int jt = 0; jt < 4; ++jt) {
      const short8 kf = *reinterpret_cast<const short8*>(&ks[jt * 16 + m16][quad * 8]);
      sacc[jt] = __builtin_amdgcn_mfma_f32_16x16x32_bf16(qfrag, kf, (f32x4){0.f,0.f,0.f,0.f}, 0, 0, 0);
    }

    // online softmax per row r (i = wave*16 + quad*4 + r); 16 lanes share a row
    float alpha[4];
    #pragma unroll
    for (int r = 0; r < 4; ++r) {
      float s0 = sacc[0][r] * scale, s1 = sacc[1][r] * scale;
      float s2 = sacc[2][r] * scale, s3 = sacc[3][r] * scale;
      float mx = fmaxf(fmaxf(s0, s1), fmaxf(s2, s3));
      mx = fmaxf(mx, __shfl_xor(mx, 1));
      mx = fmaxf(mx, __shfl_xor(mx, 2));
      mx = fmaxf(mx, __shfl_xor(mx, 4));
      mx = fmaxf(mx, __shfl_xor(mx, 8));
      const float mn = fmaxf(mreg[r], mx);
      alpha[r] = __expf(mreg[r] - mn);
      const float p0 = __expf(s0 - mn), p1 = __expf(s1 - mn);
      const float p2 = __expf(s2 - mn), p3 = __expf(s3 - mn);
      float rs = p0 + p1 + p2 + p3;
      rs += __shfl_xor(rs, 1); rs += __shfl_xor(rs, 2);
      rs += __shfl_xor(rs, 4); rs += __shfl_xor(rs, 8);
      lreg[r] = lreg[r] * alpha[r] + rs;
      mreg[r] = mn;
      const int irow = wave * 16 + quad * 4 + r;
      ps[irow][m16]      = (short)f2b(p0);
      ps[irow][16 + m16] = (short)f2b(p1);
      ps[irow][32 + m16] = (short)f2b(p2);
      ps[irow][48 + m16] = (short)f2b(p3);
    }
    // rescale O by alpha (rows match: quad*4+r)
    #pragma unroll
    for (int dt = 0; dt < 4; ++dt)
      #pragma unroll
      for (int r = 0; r < 4; ++r) oacc[dt][r] *= alpha[r];

    // PV: Y^T[i][d] += P[i][j] * V^T[j][d].  ps rows are wave-private;
    // intra-wave ds_write->ds_read ordering handled by compiler waitcnt.
    const short8 pa0 = *reinterpret_cast<const short8*>(&ps[wave * 16 + m16][quad * 8]);
    const short8 pa1 = *reinterpret_cast<const short8*>(&ps[wave * 16 + m16][32 + quad * 8]);
    #pragma unroll
    for (int dt = 0; dt < 4; ++dt) {
      const short8 v0 = *reinterpret_cast<const short8*>(&vs[dt * 16 + m16][quad * 8]);
      const short8 v1 = *reinterpret_cast<const short8*>(&vs[dt * 16 + m16][32 + quad * 8]);
      oacc[dt] = __builtin_amdgcn_mfma_f32_16x16x32_bf16(pa0, v0, oacc[dt], 0, 0, 0);
      oacc[dt] = __builtin_amdgcn_mfma_f32_16x16x32_bf16(pa1, v1, oacc[dt], 0, 0, 0);
    }
  }

  float li[4];
  #pragma unroll
  for (int r = 0; r < 4; ++r) li[r] = 1.0f / lreg[r];
  const int b = bh >> 2, h = bh & 3;
  #pragma unroll
  for (int dt = 0; dt < 4; ++dt) {
    const int c = h * 64 + dt * 16 + m16;
    float4 ov;
    ov.x = oacc[dt][0] * li[0]; ov.y = oacc[dt][1] * li[1];
    ov.z = oacc[dt][2] * li[2]; ov.w = oacc[dt][3] * li[3];
    *reinterpret_cast<float4*>(y + ((size_t)(b * 256 + c)) * NSP + i0 + wave * 16 + quad * 4) = ov;
  }
}

// ---------------- Kernel 3: y += BN(depthwise3x3(v)) ----------------
__global__ __launch_bounds__(256) void pe_kernel(
    const unsigned short* __restrict__ vb,         // (B,256,64,64) bf16
    const float* __restrict__ pw,
    const float* __restrict__ gg,
    const float* __restrict__ bb,
    const float* __restrict__ mm,
    const float* __restrict__ vv,
    float* __restrict__ y)
{
  const int bc = blockIdx.x;        // b*256 + c
  const int c  = bc & 255;
  const unsigned short* vp = vb + (size_t)bc * 4096;
  float w9[9];
  #pragma unroll
  for (int i = 0; i < 9; ++i) w9[i] = pw[c * 9 + i];
  const float sc = gg[c] * rsqrtf(vv[c] + BEPS);
  const float bi = bb[c] - mm[c] * sc;
  for (int p = threadIdx.x; p < 4096; p += 256) {
    const int py = p >> 6, px = p & 63;
    float sum = 0.f;
    #pragma unroll
    for (int ky = -1; ky <= 1; ++ky) {
      const int yy = py + ky;
      if (yy < 0 || yy > 63) continue;
      #pragma unroll
      for (int kx = -1; kx <= 1; ++kx) {
        const int xx = px + kx;
        if (xx < 0 || xx > 63) continue;
        sum += b2f(vp[yy * 64 + xx]) * w9[(ky + 1) * 3 + (kx + 1)];
      }
    }
    y[(size_t)bc * 4096 + p] += sum * sc + bi;
  }
}

// ---------------- Kernel 4: out = BN(conv1x1(y)) -> f32 ----------------
__global__ __launch_bounds__(256) void proj_kernel(
    const float* __restrict__ yin,
    const float* __restrict__ w,
    const float* __restrict__ gg,
    const float* __restrict__ bb,
    const float* __restrict__ mm,
    const float* __restrict__ vv,
    float* __restrict__ out)
{
  const int n0  = blockIdx.x * 64;
  const int co0 = blockIdx.y * 64;
  const int b   = blockIdx.z;
  const int t   = threadIdx.x;
  const int tx  = t & 15, ty = t >> 4;
  __shared__ __align__(16) float xs[32][68];
  __shared__ float wst[32][69];
  float acc[4][4] = {};
  for (int k0 = 0; k0 < 256; k0 += 32) {
    {
      int nl = t & 63, kk = t >> 6;
      #pragma unroll
      for (int r = 0; r < 8; ++r, kk += 4)
        xs[kk][nl] = yin[((size_t)(b * 256 + k0 + kk)) * NSP + n0 + nl];
      int kk2 = t & 31, co = t >> 5;
      #pragma unroll
      for (int r = 0; r < 8; ++r, co += 8)
        wst[kk2][co] = w[(size_t)(co0 + co) * 256 + k0 + kk2];
    }
    __syncthreads();
    #pragma unroll 8
    for (int kk = 0; kk < 32; ++kk) {
      const float4 xv = *reinterpret_cast<const float4*>(&xs[kk][tx * 4]);
      const float xa[4] = {xv.x, xv.y, xv.z, xv.w};
      float wr[4];
      #pragma unroll
      for (int cc = 0; cc < 4; ++cc) wr[cc] = wst[kk][ty * 4 + cc];
      #pragma unroll
      for (int cc = 0; cc < 4; ++cc)
        #pragma unroll
        for (int nn = 0; nn < 4; ++nn) acc[cc][nn] += wr[cc] * xa[nn];
    }
    __syncthreads();
  }
  #pragma unroll
  for (int cc = 0; cc < 4; ++cc) {
    const int c  = co0 + ty * 4 + cc;
    const float sc = gg[c] * rsqrtf(vv[c] + BEPS);
    const float bi = bb[c] - mm[c] * sc;
    float4 ov;
    ov.x = acc[cc][0] * sc + bi; ov.y = acc[cc][1] * sc + bi;
    ov.z = acc[cc][2] * sc + bi; ov.w = acc[cc][3] * sc + bi;
    *reinterpret_cast<float4*>(out + ((size_t)(b * 256 + c)) * NSP + n0 + tx * 4) = ov;
  }
}

extern "C" void kernel_launch(void* const* d_in, const int* in_sizes, int n_in,
                              void* d_out, int out_size, void* d_ws, size_t ws_size,
                              hipStream_t stream)
{
  const float* x      = (const float*)d_in[0];
  const float* qkv_w  = (const float*)d_in[1];
  const float* qkv_g  = (const float*)d_in[2];
  const float* qkv_b  = (const float*)d_in[3];
  const float* qkv_m  = (const float*)d_in[4];
  const float* qkv_v  = (const float*)d_in[5];
  const float* proj_w = (const float*)d_in[6];
  const float* proj_g = (const float*)d_in[7];
  const float* proj_b = (const float*)d_in[8];
  const float* proj_m = (const float*)d_in[9];
  const float* proj_v = (const float*)d_in[10];
  const float* pe_w   = (const float*)d_in[11];
  const float* pe_g   = (const float*)d_in[12];
  const float* pe_b   = (const float*)d_in[13];
  const float* pe_m   = (const float*)d_in[14];
  const float* pe_v   = (const float*)d_in[15];
  float* out = (float*)d_out;

  unsigned short* qb = (unsigned short*)d_ws;          // 8*4096*32 bf16 = 2MB
  unsigned short* kb = qb + (size_t)8 * NSP * 32;      // 2MB
  unsigned short* vb = kb + (size_t)8 * NSP * 32;      // 8*64*4096 bf16 = 4MB
  float* yy = (float*)(vb + (size_t)8 * 64 * NSP);     // 8MB f32

  qkv_kernel<<<dim3(64, 8, 2), 256, 0, stream>>>(x, qkv_w, qkv_g, qkv_b, qkv_m, qkv_v,
                                                 qb, kb, vb);
  attn_kernel<<<dim3(64, 8), 256, 0, stream>>>(qb, kb, vb, yy);
  pe_kernel<<<dim3(512), 256, 0, stream>>>(vb, pe_w, pe_g, pe_b, pe_m, pe_v, yy);
  proj_kernel<<<dim3(64, 4, 2), 256, 0, stream>>>(yy, proj_w, proj_g, proj_b, proj_m, proj_v,
                                                  out);
}

// Round 5
// 277.904 us; speedup vs baseline: 2.3499x; 1.2966x over previous
//
#include <hip/hip_runtime.h>
#include <hip/hip_bf16.h>

#define NSP 4096
#define BEPS 1e-5f
#define JSPLIT 4
#define JCHUNK (NSP / JSPLIT)

using short8  = __attribute__((ext_vector_type(8))) short;
using f32x4   = __attribute__((ext_vector_type(4))) float;

// scale * log2(e) : softmax exp(s*scale) == exp2(s*SCALE_LOG2E)
#define SCALE_LOG2E 0.25500526940103816f

__device__ __forceinline__ float b2f(unsigned short u) {
  return __uint_as_float(((unsigned)u) << 16);
}
// float -> bf16 bits, round-nearest-even
__device__ __forceinline__ unsigned short f2b(float x) {
  unsigned u = __float_as_uint(x);
  u += 0x7fffu + ((u >> 16) & 1u);
  return (unsigned short)(u >> 16);
}
__device__ __forceinline__ unsigned pk_bf16(float a, float b) {
  return ((unsigned)f2b(b) << 16) | (unsigned)f2b(a);
}

// ---------------- Kernel 1: qkv = BN(conv1x1(x)) ; split into q,k,v (bf16 outs) --------
// q,k: (bh, 4096 i, 32 d) bf16 (i-major)   v: (bh, 64 d, 4096 j) bf16 (d-major)
__global__ __launch_bounds__(256) void qkv_kernel(
    const float* __restrict__ x,
    const float* __restrict__ w,
    const float* __restrict__ gg,
    const float* __restrict__ bb,
    const float* __restrict__ mm,
    const float* __restrict__ vv,
    unsigned short* __restrict__ qb, unsigned short* __restrict__ kb,
    unsigned short* __restrict__ vb)
{
  const int n0  = blockIdx.x * 64;
  const int co0 = blockIdx.y * 64;
  const int b   = blockIdx.z;
  const int t   = threadIdx.x;
  const int tx  = t & 15, ty = t >> 4;
  __shared__ __align__(16) float xs[32][68];   // [k][n]
  __shared__ float wst[32][69];                // [k][co]
  float acc[4][4] = {};
  for (int k0 = 0; k0 < 256; k0 += 32) {
    {
      int nl = t & 63, kk = t >> 6;
      #pragma unroll
      for (int r = 0; r < 8; ++r, kk += 4)
        xs[kk][nl] = x[((size_t)(b * 256 + k0 + kk)) * NSP + n0 + nl];
      int kk2 = t & 31, co = t >> 5;
      #pragma unroll
      for (int r = 0; r < 8; ++r, co += 8)
        wst[kk2][co] = w[(size_t)(co0 + co) * 256 + k0 + kk2];
    }
    __syncthreads();
    #pragma unroll 8
    for (int kk = 0; kk < 32; ++kk) {
      const float4 xv = *reinterpret_cast<const float4*>(&xs[kk][tx * 4]);
      const float xa[4] = {xv.x, xv.y, xv.z, xv.w};
      float wr[4];
      #pragma unroll
      for (int cc = 0; cc < 4; ++cc) wr[cc] = wst[kk][ty * 4 + cc];
      #pragma unroll
      for (int cc = 0; cc < 4; ++cc)
        #pragma unroll
        for (int nn = 0; nn < 4; ++nn) acc[cc][nn] += wr[cc] * xa[nn];
    }
    __syncthreads();
  }
  // BN epilogue
  float ob[4][4];  // [cc][nn]
  const int c0 = co0 + ty * 4;
  #pragma unroll
  for (int cc = 0; cc < 4; ++cc) {
    const int c  = c0 + cc;
    const float sc = gg[c] * rsqrtf(vv[c] + BEPS);
    const float bi = bb[c] - mm[c] * sc;
    #pragma unroll
    for (int nn = 0; nn < 4; ++nn) ob[cc][nn] = acc[cc][nn] * sc + bi;
  }
  const int head = c0 >> 7, r = c0 & 127;
  const int bh = b * 4 + head;
  if (r < 64) {   // q or k: (bh, i, d) i-major; 4 consecutive d per thread -> 8B stores
    unsigned short* dst = (r < 32) ? qb : kb;
    const int d0 = r & 31;
    #pragma unroll
    for (int nn = 0; nn < 4; ++nn) {
      const int i = n0 + tx * 4 + nn;
      uint2 pk2;
      pk2.x = pk_bf16(ob[0][nn], ob[1][nn]);
      pk2.y = pk_bf16(ob[2][nn], ob[3][nn]);
      *reinterpret_cast<uint2*>(dst + ((size_t)bh * NSP + i) * 32 + d0) = pk2;
    }
  } else {        // v: (bh, d, j) d-major; 4 consecutive j per thread -> 8B stores
    #pragma unroll
    for (int cc = 0; cc < 4; ++cc) {
      const int d = (r - 64) + cc;
      uint2 pk2;
      pk2.x = pk_bf16(ob[cc][0], ob[cc][1]);
      pk2.y = pk_bf16(ob[cc][2], ob[cc][3]);
      *reinterpret_cast<uint2*>(vb + ((size_t)(bh * 64 + d)) * NSP + n0 + tx * 4) = pk2;
    }
  }
}

// ---------------- Kernel 2: MFMA flash attention, split over j ----------------
// Per block: 64 i x 1024 j for one (bh, split). Fixed-max softmax (no running max),
// deferred l. Outputs unnormalized Opart (bf16, [split][bh][d][i]) + lpart (f32).
__global__ __launch_bounds__(256) void attn_kernel(
    const unsigned short* __restrict__ qb, const unsigned short* __restrict__ kb,
    const unsigned short* __restrict__ vb,
    unsigned short* __restrict__ Opart, float* __restrict__ lpart)
{
  const int i0    = blockIdx.x * 64;
  const int bh    = blockIdx.y;
  const int split = blockIdx.z;
  const int jbase = split * JCHUNK;
  const int t  = threadIdx.x;
  const int lane = t & 63, wave = t >> 6;
  const int m16 = lane & 15, quad = lane >> 4;
  __shared__ __align__(16) short qs[64][40];   // [i][d]
  __shared__ __align__(16) short ks[64][40];   // [j][d]
  __shared__ __align__(16) short vs[64][72];   // [d][j]
  __shared__ __align__(16) short ps[64][72];   // [i][j] bf16 P, wave-private rows

  const int srow = t >> 2, schunk = t & 3;
  {  // stage Q once: 64 rows x 32 bf16
    const unsigned short* qp = qb + ((size_t)bh * NSP + i0) * 32;
    *reinterpret_cast<float4*>(&qs[srow][schunk * 8]) =
        *reinterpret_cast<const float4*>(qp + srow * 32 + schunk * 8);
  }
  __syncthreads();
  const short8 qfrag = *reinterpret_cast<const short8*>(&qs[wave * 16 + m16][quad * 8]);

  float rsum = 0.f;
  f32x4 oacc[4] = {};

  for (int jt0 = 0; jt0 < JCHUNK; jt0 += 64) {
    const int j0 = jbase + jt0;
    __syncthreads();  // prev-iter ks/vs reads done before restaging
    {
      const unsigned short* kp = kb + ((size_t)bh * NSP + j0) * 32;
      *reinterpret_cast<float4*>(&ks[srow][schunk * 8]) =
          *reinterpret_cast<const float4*>(kp + srow * 32 + schunk * 8);
      const unsigned short* vp = vb + (size_t)bh * 64 * NSP + j0;
      *reinterpret_cast<float4*>(&vs[srow][schunk * 16]) =
          *reinterpret_cast<const float4*>(vp + (size_t)srow * NSP + schunk * 16);
      *reinterpret_cast<float4*>(&vs[srow][schunk * 16 + 8]) =
          *reinterpret_cast<const float4*>(vp + (size_t)srow * NSP + schunk * 16 + 8);
    }
    __syncthreads();

    // S^T tile: A = K (m=j), B = Q (n=i) -> lane holds i = wave*16+m16, rows j.
    f32x4 sacc[4];
    #pragma unroll
    for (int jt = 0; jt < 4; ++jt) {
      const short8 kf = *reinterpret_cast<const short8*>(&ks[jt * 16 + m16][quad * 8]);
      sacc[jt] = __builtin_amdgcn_mfma_f32_16x16x32_bf16(kf, qfrag, (f32x4){0.f,0.f,0.f,0.f}, 0, 0, 0);
    }

    // softmax (fixed max=0): p = exp2(s * SCALE_LOG2E); all 16 values belong to row i.
    // P[i][j] write: 4 consecutive j per jt -> packed 8B LDS write.
    #pragma unroll
    for (int jt = 0; jt < 4; ++jt) {
      float p0 = __builtin_amdgcn_exp2f(sacc[jt][0] * SCALE_LOG2E);
      float p1 = __builtin_amdgcn_exp2f(sacc[jt][1] * SCALE_LOG2E);
      float p2 = __builtin_amdgcn_exp2f(sacc[jt][2] * SCALE_LOG2E);
      float p3 = __builtin_amdgcn_exp2f(sacc[jt][3] * SCALE_LOG2E);
      rsum += (p0 + p1) + (p2 + p3);
      uint2 pk2;
      pk2.x = pk_bf16(p0, p1);
      pk2.y = pk_bf16(p2, p3);
      *reinterpret_cast<uint2*>(&ps[wave * 16 + m16][jt * 16 + quad * 4]) = pk2;
    }

    // PV: O[i][d] += P[i][j] V[j][d]; A = P (ps rows wave-private), B = V^T.
    const short8 pa0 = *reinterpret_cast<const short8*>(&ps[wave * 16 + m16][quad * 8]);
    const short8 pa1 = *reinterpret_cast<const short8*>(&ps[wave * 16 + m16][32 + quad * 8]);
    #pragma unroll
    for (int dt = 0; dt < 4; ++dt) {
      const short8 v0 = *reinterpret_cast<const short8*>(&vs[dt * 16 + m16][quad * 8]);
      const short8 v1 = *reinterpret_cast<const short8*>(&vs[dt * 16 + m16][32 + quad * 8]);
      oacc[dt] = __builtin_amdgcn_mfma_f32_16x16x32_bf16(pa0, v0, oacc[dt], 0, 0, 0);
      oacc[dt] = __builtin_amdgcn_mfma_f32_16x16x32_bf16(pa1, v1, oacc[dt], 0, 0, 0);
    }
  }

  // finalize l for this block's j-range: reduce across quads (same m16)
  rsum += __shfl_xor(rsum, 16);
  rsum += __shfl_xor(rsum, 32);
  if (quad == 0)
    lpart[((size_t)split * 8 + bh) * NSP + i0 + wave * 16 + m16] = rsum;

  // store unnormalized O partial as bf16: [split][bh][d][i], 4 consecutive i -> 8B
  #pragma unroll
  for (int dt = 0; dt < 4; ++dt) {
    const int d = dt * 16 + m16;
    uint2 pk2;
    pk2.x = pk_bf16(oacc[dt][0], oacc[dt][1]);
    pk2.y = pk_bf16(oacc[dt][2], oacc[dt][3]);
    *reinterpret_cast<uint2*>(Opart +
        (((size_t)split * 8 + bh) * 64 + d) * NSP + i0 + wave * 16 + quad * 4) = pk2;
  }
}

// ---------------- Kernel 2b: combine partials -> y (f32) ----------------
__global__ __launch_bounds__(256) void combine_kernel(
    const unsigned short* __restrict__ Opart, const float* __restrict__ lpart,
    float* __restrict__ y)
{
  const int i  = blockIdx.x * 256 + threadIdx.x;
  const int d  = blockIdx.y;
  const int bh = blockIdx.z;
  float os = 0.f, ls = 0.f;
  #pragma unroll
  for (int s = 0; s < JSPLIT; ++s) {
    os += b2f(Opart[(((size_t)s * 8 + bh) * 64 + d) * NSP + i]);
    ls += lpart[((size_t)s * 8 + bh) * NSP + i];
  }
  const int b = bh >> 2, h = bh & 3;
  y[((size_t)(b * 256 + h * 64 + d)) * NSP + i] = os / ls;
}

// ---------------- Kernel 3: y += BN(depthwise3x3(v)) ----------------
__global__ __launch_bounds__(256) void pe_kernel(
    const unsigned short* __restrict__ vb,         // (B,256,64,64) bf16
    const float* __restrict__ pw,
    const float* __restrict__ gg,
    const float* __restrict__ bb,
    const float* __restrict__ mm,
    const float* __restrict__ vv,
    float* __restrict__ y)
{
  const int bc = blockIdx.x;        // b*256 + c
  const int c  = bc & 255;
  const unsigned short* vp = vb + (size_t)bc * 4096;
  float w9[9];
  #pragma unroll
  for (int i = 0; i < 9; ++i) w9[i] = pw[c * 9 + i];
  const float sc = gg[c] * rsqrtf(vv[c] + BEPS);
  const float bi = bb[c] - mm[c] * sc;
  for (int p = threadIdx.x; p < 4096; p += 256) {
    const int py = p >> 6, px = p & 63;
    float sum = 0.f;
    #pragma unroll
    for (int ky = -1; ky <= 1; ++ky) {
      const int yy = py + ky;
      if (yy < 0 || yy > 63) continue;
      #pragma unroll
      for (int kx = -1; kx <= 1; ++kx) {
        const int xx = px + kx;
        if (xx < 0 || xx > 63) continue;
        sum += b2f(vp[yy * 64 + xx]) * w9[(ky + 1) * 3 + (kx + 1)];
      }
    }
    y[(size_t)bc * 4096 + p] += sum * sc + bi;
  }
}

// ---------------- Kernel 4: out = BN(conv1x1(y)) -> f32 ----------------
__global__ __launch_bounds__(256) void proj_kernel(
    const float* __restrict__ yin,
    const float* __restrict__ w,
    const float* __restrict__ gg,
    const float* __restrict__ bb,
    const float* __restrict__ mm,
    const float* __restrict__ vv,
    float* __restrict__ out)
{
  const int n0  = blockIdx.x * 64;
  const int co0 = blockIdx.y * 64;
  const int b   = blockIdx.z;
  const int t   = threadIdx.x;
  const int tx  = t & 15, ty = t >> 4;
  __shared__ __align__(16) float xs[32][68];
  __shared__ float wst[32][69];
  float acc[4][4] = {};
  for (int k0 = 0; k0 < 256; k0 += 32) {
    {
      int nl = t & 63, kk = t >> 6;
      #pragma unroll
      for (int r = 0; r < 8; ++r, kk += 4)
        xs[kk][nl] = yin[((size_t)(b * 256 + k0 + kk)) * NSP + n0 + nl];
      int kk2 = t & 31, co = t >> 5;
      #pragma unroll
      for (int r = 0; r < 8; ++r, co += 8)
        wst[kk2][co] = w[(size_t)(co0 + co) * 256 + k0 + kk2];
    }
    __syncthreads();
    #pragma unroll 8
    for (int kk = 0; kk < 32; ++kk) {
      const float4 xv = *reinterpret_cast<const float4*>(&xs[kk][tx * 4]);
      const float xa[4] = {xv.x, xv.y, xv.z, xv.w};
      float wr[4];
      #pragma unroll
      for (int cc = 0; cc < 4; ++cc) wr[cc] = wst[kk][ty * 4 + cc];
      #pragma unroll
      for (int cc = 0; cc < 4; ++cc)
        #pragma unroll
        for (int nn = 0; nn < 4; ++nn) acc[cc][nn] += wr[cc] * xa[nn];
    }
    __syncthreads();
  }
  #pragma unroll
  for (int cc = 0; cc < 4; ++cc) {
    const int c  = co0 + ty * 4 + cc;
    const float sc = gg[c] * rsqrtf(vv[c] + BEPS);
    const float bi = bb[c] - mm[c] * sc;
    float4 ov;
    ov.x = acc[cc][0] * sc + bi; ov.y = acc[cc][1] * sc + bi;
    ov.z = acc[cc][2] * sc + bi; ov.w = acc[cc][3] * sc + bi;
    *reinterpret_cast<float4*>(out + ((size_t)(b * 256 + c)) * NSP + n0 + tx * 4) = ov;
  }
}

extern "C" void kernel_launch(void* const* d_in, const int* in_sizes, int n_in,
                              void* d_out, int out_size, void* d_ws, size_t ws_size,
                              hipStream_t stream)
{
  const float* x      = (const float*)d_in[0];
  const float* qkv_w  = (const float*)d_in[1];
  const float* qkv_g  = (const float*)d_in[2];
  const float* qkv_b  = (const float*)d_in[3];
  const float* qkv_m  = (const float*)d_in[4];
  const float* qkv_v  = (const float*)d_in[5];
  const float* proj_w = (const float*)d_in[6];
  const float* proj_g = (const float*)d_in[7];
  const float* proj_b = (const float*)d_in[8];
  const float* proj_m = (const float*)d_in[9];
  const float* proj_v = (const float*)d_in[10];
  const float* pe_w   = (const float*)d_in[11];
  const float* pe_g   = (const float*)d_in[12];
  const float* pe_b   = (const float*)d_in[13];
  const float* pe_m   = (const float*)d_in[14];
  const float* pe_v   = (const float*)d_in[15];
  float* out = (float*)d_out;

  unsigned short* qb = (unsigned short*)d_ws;          // 8*4096*32 bf16 = 2MB
  unsigned short* kb = qb + (size_t)8 * NSP * 32;      // 2MB
  unsigned short* vb = kb + (size_t)8 * NSP * 32;      // 4MB
  float* yy = (float*)(vb + (size_t)8 * 64 * NSP);     // 8MB f32
  unsigned short* Opart = (unsigned short*)(yy + (size_t)2 * 256 * NSP);  // 16MB bf16
  float* lpart = (float*)(Opart + (size_t)JSPLIT * 8 * 64 * NSP);         // 512KB

  qkv_kernel<<<dim3(64, 8, 2), 256, 0, stream>>>(x, qkv_w, qkv_g, qkv_b, qkv_m, qkv_v,
                                                 qb, kb, vb);
  attn_kernel<<<dim3(64, 8, JSPLIT), 256, 0, stream>>>(qb, kb, vb, Opart, lpart);
  combine_kernel<<<dim3(16, 64, 8), 256, 0, stream>>>(Opart, lpart, yy);
  pe_kernel<<<dim3(512), 256, 0, stream>>>(vb, pe_w, pe_g, pe_b, pe_m, pe_v, yy);
  proj_kernel<<<dim3(64, 4, 2), 256, 0, stream>>>(yy, proj_w, proj_g, proj_b, proj_m, proj_v,
                                                  out);
}

// Round 6
// 177.387 us; speedup vs baseline: 3.6815x; 1.5667x over previous
//
#include <hip/hip_runtime.h>
#include <hip/hip_bf16.h>

#define NSP 4096
#define BEPS 1e-5f
#define JSPLIT 4
#define JCHUNK (NSP / JSPLIT)

using short8  = __attribute__((ext_vector_type(8))) short;
using f32x4   = __attribute__((ext_vector_type(4))) float;

// scale * log2(e) : softmax exp(s*scale) == exp2(s*SCALE_LOG2E)
#define SCALE_LOG2E 0.25500526940103816f

__device__ __forceinline__ float b2f(unsigned short u) {
  return __uint_as_float(((unsigned)u) << 16);
}
// float -> bf16 bits, round-nearest-even
__device__ __forceinline__ unsigned short f2b(float x) {
  unsigned u = __float_as_uint(x);
  u += 0x7fffu + ((u >> 16) & 1u);
  return (unsigned short)(u >> 16);
}
__device__ __forceinline__ unsigned pk_bf16(float a, float b) {
  return ((unsigned)f2b(b) << 16) | (unsigned)f2b(a);
}

// ---------------- Kernel 0a: cast weights to bf16 ----------------
__global__ __launch_bounds__(256) void cast_w_kernel(
    const float* __restrict__ qkv_w, const float* __restrict__ proj_w,
    unsigned short* __restrict__ wqb, unsigned short* __restrict__ wpb)
{
  const int i = blockIdx.x * 256 + threadIdx.x;   // grid 768 -> 196608 threads
  if (i < 131072)       wqb[i] = f2b(qkv_w[i]);
  else                  wpb[i - 131072] = f2b(proj_w[i - 131072]);
}

// ---------------- Kernel 0b: transpose-cast x -> xT (b, n, c) bf16 ----------------
__global__ __launch_bounds__(256) void transpose_x_kernel(
    const float* __restrict__ x, unsigned short* __restrict__ xT)
{
  const int n0 = blockIdx.x * 64, c0 = blockIdx.y * 64, b = blockIdx.z;
  __shared__ __align__(16) unsigned short tx[64][72];   // [n][c]
  const int t = threadIdx.x;
  const int row = t >> 2;        // c index within tile
  const int seg = t & 3;         // 16 n each
  {
    const float* xp = x + ((size_t)(b * 256 + c0 + row)) * NSP + n0 + seg * 16;
    #pragma unroll
    for (int q4 = 0; q4 < 4; ++q4) {
      const float4 a = *reinterpret_cast<const float4*>(xp + q4 * 4);
      tx[seg * 16 + q4 * 4 + 0][row] = f2b(a.x);
      tx[seg * 16 + q4 * 4 + 1][row] = f2b(a.y);
      tx[seg * 16 + q4 * 4 + 2][row] = f2b(a.z);
      tx[seg * 16 + q4 * 4 + 3][row] = f2b(a.w);
    }
  }
  __syncthreads();
  const int nrow = t >> 2, ch = t & 3;
  unsigned short* op = xT + ((size_t)(b * NSP + n0 + nrow)) * 256 + c0 + ch * 16;
  *reinterpret_cast<float4*>(op)     = *reinterpret_cast<const float4*>(&tx[nrow][ch * 16]);
  *reinterpret_cast<float4*>(op + 8) = *reinterpret_cast<const float4*>(&tx[nrow][ch * 16 + 8]);
}

// ---------------- Kernel 1: MFMA qkv GEMM + BN + scatter ----------------
// C[co, n] = Wq[co, k] . X^T[n, k] ; even co-tile -> q/k (i-major), odd -> v (d-major)
__global__ __launch_bounds__(256) void qkv_gemm_kernel(
    const unsigned short* __restrict__ xT, const unsigned short* __restrict__ wqb,
    const float* __restrict__ gg, const float* __restrict__ bb,
    const float* __restrict__ mm, const float* __restrict__ vv,
    unsigned short* __restrict__ qb, unsigned short* __restrict__ kb,
    unsigned short* __restrict__ vb)
{
  const int n0 = blockIdx.x * 64;
  const int cotile = blockIdx.y;           // 8 tiles of 64 co
  const int b = blockIdx.z;
  const int co0 = cotile * 64;
  const int t = threadIdx.x;
  __shared__ __align__(16) unsigned short wt[64][136];   // [co][k-chunk 128]
  __shared__ __align__(16) unsigned short xt[64][136];   // [n][k-chunk 128]
  const int lane = t & 63, wave = t >> 6;
  const int m16 = lane & 15, quad = lane >> 4;
  const int row = t >> 2, seg = t & 3;

  f32x4 acc[4] = {};
  for (int kc = 0; kc < 2; ++kc) {
    if (kc) __syncthreads();
    {
      const unsigned short* wp = wqb + (size_t)(co0 + row) * 256 + kc * 128 + seg * 32;
      const unsigned short* xp = xT + ((size_t)(b * NSP + n0 + row)) * 256 + kc * 128 + seg * 32;
      #pragma unroll
      for (int u = 0; u < 4; ++u) {
        *reinterpret_cast<float4*>(&wt[row][seg * 32 + u * 8]) =
            *reinterpret_cast<const float4*>(wp + u * 8);
        *reinterpret_cast<float4*>(&xt[row][seg * 32 + u * 8]) =
            *reinterpret_cast<const float4*>(xp + u * 8);
      }
    }
    __syncthreads();
    if ((cotile & 1) == 0) {   // q/k: A = W (m=co), B = X (n=spatial)
      #pragma unroll
      for (int ks = 0; ks < 4; ++ks) {
        const short8 af = *reinterpret_cast<const short8*>(&wt[wave * 16 + m16][ks * 32 + quad * 8]);
        #pragma unroll
        for (int nt = 0; nt < 4; ++nt) {
          const short8 bf = *reinterpret_cast<const short8*>(&xt[nt * 16 + m16][ks * 32 + quad * 8]);
          acc[nt] = __builtin_amdgcn_mfma_f32_16x16x32_bf16(af, bf, acc[nt], 0, 0, 0);
        }
      }
    } else {                   // v: swapped -> A = X (m=spatial), B = W (n=co)
      #pragma unroll
      for (int ks = 0; ks < 4; ++ks) {
        const short8 bf = *reinterpret_cast<const short8*>(&wt[wave * 16 + m16][ks * 32 + quad * 8]);
        #pragma unroll
        for (int nt = 0; nt < 4; ++nt) {
          const short8 af = *reinterpret_cast<const short8*>(&xt[nt * 16 + m16][ks * 32 + quad * 8]);
          acc[nt] = __builtin_amdgcn_mfma_f32_16x16x32_bf16(af, bf, acc[nt], 0, 0, 0);
        }
      }
    }
  }

  const int head = cotile >> 1;
  const int bh = b * 4 + head;
  if ((cotile & 1) == 0) {
    // lane: n = n0 + nt*16 + m16 ; co = co0 + wave*16 + quad*4 + r
    const int coh = wave * 16 + quad * 4;   // 0..63 within head half (q if <32 else k)
    float sc[4], bi[4];
    #pragma unroll
    for (int r = 0; r < 4; ++r) {
      const int c = co0 + coh + r;
      sc[r] = gg[c] * rsqrtf(vv[c] + BEPS);
      bi[r] = bb[c] - mm[c] * sc[r];
    }
    unsigned short* dst = (coh < 32) ? qb : kb;
    const int d0 = coh & 31;
    #pragma unroll
    for (int nt = 0; nt < 4; ++nt) {
      const int i = n0 + nt * 16 + m16;
      uint2 pk2;
      pk2.x = pk_bf16(acc[nt][0] * sc[0] + bi[0], acc[nt][1] * sc[1] + bi[1]);
      pk2.y = pk_bf16(acc[nt][2] * sc[2] + bi[2], acc[nt][3] * sc[3] + bi[3]);
      *reinterpret_cast<uint2*>(dst + ((size_t)bh * NSP + i) * 32 + d0) = pk2;
    }
  } else {
    // lane: co = co0 + wave*16 + m16 (d = wave*16+m16) ; j = n0 + nt*16 + quad*4 + r
    const int c = co0 + wave * 16 + m16;
    const float sc = gg[c] * rsqrtf(vv[c] + BEPS);
    const float bi = bb[c] - mm[c] * sc;
    const int d = wave * 16 + m16;
    #pragma unroll
    for (int nt = 0; nt < 4; ++nt) {
      const int j = n0 + nt * 16 + quad * 4;
      uint2 pk2;
      pk2.x = pk_bf16(acc[nt][0] * sc + bi, acc[nt][1] * sc + bi);
      pk2.y = pk_bf16(acc[nt][2] * sc + bi, acc[nt][3] * sc + bi);
      *reinterpret_cast<uint2*>(vb + ((size_t)(bh * 64 + d)) * NSP + j) = pk2;
    }
  }
}

// ---------------- Kernel 2: MFMA flash attention, split over j (UNCHANGED) ----------------
__global__ __launch_bounds__(256) void attn_kernel(
    const unsigned short* __restrict__ qb, const unsigned short* __restrict__ kb,
    const unsigned short* __restrict__ vb,
    unsigned short* __restrict__ Opart, float* __restrict__ lpart)
{
  const int i0    = blockIdx.x * 64;
  const int bh    = blockIdx.y;
  const int split = blockIdx.z;
  const int jbase = split * JCHUNK;
  const int t  = threadIdx.x;
  const int lane = t & 63, wave = t >> 6;
  const int m16 = lane & 15, quad = lane >> 4;
  __shared__ __align__(16) short qs[64][40];   // [i][d]
  __shared__ __align__(16) short ks[64][40];   // [j][d]
  __shared__ __align__(16) short vs[64][72];   // [d][j]
  __shared__ __align__(16) short ps[64][72];   // [i][j] bf16 P, wave-private rows

  const int srow = t >> 2, schunk = t & 3;
  {  // stage Q once: 64 rows x 32 bf16
    const unsigned short* qp = qb + ((size_t)bh * NSP + i0) * 32;
    *reinterpret_cast<float4*>(&qs[srow][schunk * 8]) =
        *reinterpret_cast<const float4*>(qp + srow * 32 + schunk * 8);
  }
  __syncthreads();
  const short8 qfrag = *reinterpret_cast<const short8*>(&qs[wave * 16 + m16][quad * 8]);

  float rsum = 0.f;
  f32x4 oacc[4] = {};

  for (int jt0 = 0; jt0 < JCHUNK; jt0 += 64) {
    const int j0 = jbase + jt0;
    __syncthreads();
    {
      const unsigned short* kp = kb + ((size_t)bh * NSP + j0) * 32;
      *reinterpret_cast<float4*>(&ks[srow][schunk * 8]) =
          *reinterpret_cast<const float4*>(kp + srow * 32 + schunk * 8);
      const unsigned short* vp = vb + (size_t)bh * 64 * NSP + j0;
      *reinterpret_cast<float4*>(&vs[srow][schunk * 16]) =
          *reinterpret_cast<const float4*>(vp + (size_t)srow * NSP + schunk * 16);
      *reinterpret_cast<float4*>(&vs[srow][schunk * 16 + 8]) =
          *reinterpret_cast<const float4*>(vp + (size_t)srow * NSP + schunk * 16 + 8);
    }
    __syncthreads();

    f32x4 sacc[4];
    #pragma unroll
    for (int jt = 0; jt < 4; ++jt) {
      const short8 kf = *reinterpret_cast<const short8*>(&ks[jt * 16 + m16][quad * 8]);
      sacc[jt] = __builtin_amdgcn_mfma_f32_16x16x32_bf16(kf, qfrag, (f32x4){0.f,0.f,0.f,0.f}, 0, 0, 0);
    }

    #pragma unroll
    for (int jt = 0; jt < 4; ++jt) {
      float p0 = __builtin_amdgcn_exp2f(sacc[jt][0] * SCALE_LOG2E);
      float p1 = __builtin_amdgcn_exp2f(sacc[jt][1] * SCALE_LOG2E);
      float p2 = __builtin_amdgcn_exp2f(sacc[jt][2] * SCALE_LOG2E);
      float p3 = __builtin_amdgcn_exp2f(sacc[jt][3] * SCALE_LOG2E);
      rsum += (p0 + p1) + (p2 + p3);
      uint2 pk2;
      pk2.x = pk_bf16(p0, p1);
      pk2.y = pk_bf16(p2, p3);
      *reinterpret_cast<uint2*>(&ps[wave * 16 + m16][jt * 16 + quad * 4]) = pk2;
    }

    const short8 pa0 = *reinterpret_cast<const short8*>(&ps[wave * 16 + m16][quad * 8]);
    const short8 pa1 = *reinterpret_cast<const short8*>(&ps[wave * 16 + m16][32 + quad * 8]);
    #pragma unroll
    for (int dt = 0; dt < 4; ++dt) {
      const short8 v0 = *reinterpret_cast<const short8*>(&vs[dt * 16 + m16][quad * 8]);
      const short8 v1 = *reinterpret_cast<const short8*>(&vs[dt * 16 + m16][32 + quad * 8]);
      oacc[dt] = __builtin_amdgcn_mfma_f32_16x16x32_bf16(pa0, v0, oacc[dt], 0, 0, 0);
      oacc[dt] = __builtin_amdgcn_mfma_f32_16x16x32_bf16(pa1, v1, oacc[dt], 0, 0, 0);
    }
  }

  rsum += __shfl_xor(rsum, 16);
  rsum += __shfl_xor(rsum, 32);
  if (quad == 0)
    lpart[((size_t)split * 8 + bh) * NSP + i0 + wave * 16 + m16] = rsum;

  #pragma unroll
  for (int dt = 0; dt < 4; ++dt) {
    const int d = dt * 16 + m16;
    uint2 pk2;
    pk2.x = pk_bf16(oacc[dt][0], oacc[dt][1]);
    pk2.y = pk_bf16(oacc[dt][2], oacc[dt][3]);
    *reinterpret_cast<uint2*>(Opart +
        (((size_t)split * 8 + bh) * 64 + d) * NSP + i0 + wave * 16 + quad * 4) = pk2;
  }
}

// ---------------- Kernel 3: fused combine + pe -> yT (b, n, c) bf16 ----------------
__global__ __launch_bounds__(256) void fuse_kernel(
    const unsigned short* __restrict__ Opart, const float* __restrict__ lpart,
    const unsigned short* __restrict__ vb,
    const float* __restrict__ pw, const float* __restrict__ pg,
    const float* __restrict__ pb, const float* __restrict__ pm,
    const float* __restrict__ pv,
    unsigned short* __restrict__ yT)
{
  const int py = blockIdx.x;       // spatial row
  const int bh = blockIdx.y;       // 8
  const int b = bh >> 2, h = bh & 3;
  const int t = threadIdx.x;
  const int d = t >> 2, seg = t & 3;      // d 0..63 ; px window = seg*16..+15
  __shared__ float lsum[64];
  __shared__ __align__(16) unsigned short yt[64][72];   // [px][d]

  if (t < 64) {
    float ls = 0.f;
    #pragma unroll
    for (int s = 0; s < JSPLIT; ++s)
      ls += lpart[((size_t)s * 8 + bh) * NSP + py * 64 + t];
    lsum[t] = ls;
  }
  __syncthreads();

  const int c = h * 64 + d;
  const int i0 = py * 64 + seg * 16;
  float os[16] = {};
  #pragma unroll
  for (int s = 0; s < JSPLIT; ++s) {
    const unsigned short* op = Opart + (((size_t)s * 8 + bh) * 64 + d) * NSP + i0;
    #pragma unroll
    for (int u = 0; u < 16; ++u) os[u] += b2f(op[u]);
  }

  float w9[9];
  #pragma unroll
  for (int i = 0; i < 9; ++i) w9[i] = pw[c * 9 + i];
  const float sc = pg[c] * rsqrtf(pv[c] + BEPS);
  const float bi = pb[c] - pm[c] * sc;
  const unsigned short* vrow = vb + ((size_t)(bh * 64 + d)) * NSP;

  float conv[16] = {};
  #pragma unroll
  for (int dy = -1; dy <= 1; ++dy) {
    const int yy = py + dy;
    if (yy < 0 || yy > 63) continue;
    float vals[18];
    #pragma unroll
    for (int u = 0; u < 18; ++u) {
      const int px = seg * 16 - 1 + u;
      vals[u] = (px >= 0 && px < 64) ? b2f(vrow[yy * 64 + px]) : 0.f;
    }
    const float wr0 = w9[(dy + 1) * 3 + 0], wr1 = w9[(dy + 1) * 3 + 1], wr2 = w9[(dy + 1) * 3 + 2];
    #pragma unroll
    for (int u = 0; u < 16; ++u)
      conv[u] += vals[u] * wr0 + vals[u + 1] * wr1 + vals[u + 2] * wr2;
  }

  #pragma unroll
  for (int u = 0; u < 16; ++u) {
    const float yv = os[u] / lsum[seg * 16 + u] + conv[u] * sc + bi;
    yt[seg * 16 + u][d] = f2b(yv);
  }
  __syncthreads();

  const int prow = t >> 2, ch = t & 3;
  unsigned short* op = yT + ((size_t)(b * NSP + py * 64 + prow)) * 256 + h * 64 + ch * 16;
  *reinterpret_cast<float4*>(op)     = *reinterpret_cast<const float4*>(&yt[prow][ch * 16]);
  *reinterpret_cast<float4*>(op + 8) = *reinterpret_cast<const float4*>(&yt[prow][ch * 16 + 8]);
}

// ---------------- Kernel 4: MFMA proj GEMM + BN -> out f32 ----------------
// out[co, n] = BN(Wp[co,k] . yT[n,k]) ; swapped orientation: lane-fixed co, float4 along n
__global__ __launch_bounds__(256) void proj_gemm_kernel(
    const unsigned short* __restrict__ yT, const unsigned short* __restrict__ wpb,
    const float* __restrict__ gg, const float* __restrict__ bb,
    const float* __restrict__ mm, const float* __restrict__ vv,
    float* __restrict__ out)
{
  const int n0 = blockIdx.x * 64;
  const int co0 = blockIdx.y * 64;   // 4 tiles
  const int b = blockIdx.z;
  const int t = threadIdx.x;
  __shared__ __align__(16) unsigned short wt[64][136];
  __shared__ __align__(16) unsigned short yt[64][136];
  const int lane = t & 63, wave = t >> 6;
  const int m16 = lane & 15, quad = lane >> 4;
  const int row = t >> 2, seg = t & 3;

  f32x4 acc[4] = {};
  for (int kc = 0; kc < 2; ++kc) {
    if (kc) __syncthreads();
    {
      const unsigned short* wp = wpb + (size_t)(co0 + row) * 256 + kc * 128 + seg * 32;
      const unsigned short* yp = yT + ((size_t)(b * NSP + n0 + row)) * 256 + kc * 128 + seg * 32;
      #pragma unroll
      for (int u = 0; u < 4; ++u) {
        *reinterpret_cast<float4*>(&wt[row][seg * 32 + u * 8]) =
            *reinterpret_cast<const float4*>(wp + u * 8);
        *reinterpret_cast<float4*>(&yt[row][seg * 32 + u * 8]) =
            *reinterpret_cast<const float4*>(yp + u * 8);
      }
    }
    __syncthreads();
    #pragma unroll
    for (int ks = 0; ks < 4; ++ks) {
      const short8 bf = *reinterpret_cast<const short8*>(&wt[wave * 16 + m16][ks * 32 + quad * 8]);
      #pragma unroll
      for (int nt = 0; nt < 4; ++nt) {
        const short8 af = *reinterpret_cast<const short8*>(&yt[nt * 16 + m16][ks * 32 + quad * 8]);
        acc[nt] = __builtin_amdgcn_mfma_f32_16x16x32_bf16(af, bf, acc[nt], 0, 0, 0);
      }
    }
  }

  const int c = co0 + wave * 16 + m16;
  const float sc = gg[c] * rsqrtf(vv[c] + BEPS);
  const float bi = bb[c] - mm[c] * sc;
  #pragma unroll
  for (int nt = 0; nt < 4; ++nt) {
    const int n = n0 + nt * 16 + quad * 4;
    float4 ov;
    ov.x = acc[nt][0] * sc + bi; ov.y = acc[nt][1] * sc + bi;
    ov.z = acc[nt][2] * sc + bi; ov.w = acc[nt][3] * sc + bi;
    *reinterpret_cast<float4*>(out + ((size_t)(b * 256 + c)) * NSP + n) = ov;
  }
}

extern "C" void kernel_launch(void* const* d_in, const int* in_sizes, int n_in,
                              void* d_out, int out_size, void* d_ws, size_t ws_size,
                              hipStream_t stream)
{
  const float* x      = (const float*)d_in[0];
  const float* qkv_w  = (const float*)d_in[1];
  const float* qkv_g  = (const float*)d_in[2];
  const float* qkv_b  = (const float*)d_in[3];
  const float* qkv_m  = (const float*)d_in[4];
  const float* qkv_v  = (const float*)d_in[5];
  const float* proj_w = (const float*)d_in[6];
  const float* proj_g = (const float*)d_in[7];
  const float* proj_b = (const float*)d_in[8];
  const float* proj_m = (const float*)d_in[9];
  const float* proj_v = (const float*)d_in[10];
  const float* pe_w   = (const float*)d_in[11];
  const float* pe_g   = (const float*)d_in[12];
  const float* pe_b   = (const float*)d_in[13];
  const float* pe_m   = (const float*)d_in[14];
  const float* pe_v   = (const float*)d_in[15];
  float* out = (float*)d_out;

  unsigned short* qb = (unsigned short*)d_ws;             // 1M elems (2MB)
  unsigned short* kb = qb + (size_t)8 * NSP * 32;         // 2MB
  unsigned short* vb = kb + (size_t)8 * NSP * 32;         // 4MB
  unsigned short* Opart = vb + (size_t)8 * 64 * NSP;      // 16MB
  float* lpart = (float*)(Opart + (size_t)JSPLIT * 8 * 64 * NSP);  // 512KB
  unsigned short* xT = (unsigned short*)(lpart + (size_t)JSPLIT * 8 * NSP);  // 4MB
  unsigned short* yT = xT + (size_t)2 * NSP * 256;        // 4MB
  unsigned short* wqb = yT + (size_t)2 * NSP * 256;       // 256KB
  unsigned short* wpb = wqb + (size_t)512 * 256;          // 128KB

  cast_w_kernel<<<dim3(768), 256, 0, stream>>>(qkv_w, proj_w, wqb, wpb);
  transpose_x_kernel<<<dim3(64, 4, 2), 256, 0, stream>>>(x, xT);
  qkv_gemm_kernel<<<dim3(64, 8, 2), 256, 0, stream>>>(xT, wqb, qkv_g, qkv_b, qkv_m, qkv_v,
                                                      qb, kb, vb);
  attn_kernel<<<dim3(64, 8, JSPLIT), 256, 0, stream>>>(qb, kb, vb, Opart, lpart);
  fuse_kernel<<<dim3(64, 8), 256, 0, stream>>>(Opart, lpart, vb,
                                               pe_w, pe_g, pe_b, pe_m, pe_v, yT);
  proj_gemm_kernel<<<dim3(64, 4, 2), 256, 0, stream>>>(yT, wpb, proj_g, proj_b, proj_m, proj_v,
                                                       out);
}

// Round 7
// 169.893 us; speedup vs baseline: 3.8439x; 1.0441x over previous
//
#include <hip/hip_runtime.h>
#include <hip/hip_bf16.h>

#define NSP 4096
#define BEPS 1e-5f
#define JSPLIT 4
#define JCHUNK (NSP / JSPLIT)

using short8  = __attribute__((ext_vector_type(8))) short;
using f32x4   = __attribute__((ext_vector_type(4))) float;

// scale * log2(e) : softmax exp(s*scale) == exp2(s*SCALE_LOG2E)
#define SCALE_LOG2E 0.25500526940103816f

__device__ __forceinline__ float b2f(unsigned short u) {
  return __uint_as_float(((unsigned)u) << 16);
}
// float -> bf16 bits, round-nearest-even
__device__ __forceinline__ unsigned short f2b(float x) {
  unsigned u = __float_as_uint(x);
  u += 0x7fffu + ((u >> 16) & 1u);
  return (unsigned short)(u >> 16);
}
__device__ __forceinline__ unsigned pk_bf16(float a, float b) {
  return ((unsigned)f2b(b) << 16) | (unsigned)f2b(a);
}

// ---------------- Kernel 0a: cast weights to bf16 ----------------
__global__ __launch_bounds__(256) void cast_w_kernel(
    const float* __restrict__ qkv_w, const float* __restrict__ proj_w,
    unsigned short* __restrict__ wqb, unsigned short* __restrict__ wpb)
{
  const int i = blockIdx.x * 256 + threadIdx.x;   // grid 768 -> 196608 threads
  if (i < 131072)       wqb[i] = f2b(qkv_w[i]);
  else                  wpb[i - 131072] = f2b(proj_w[i - 131072]);
}

// ---------------- Kernel 0b: transpose-cast x -> xT (b, n, c) bf16 ----------------
__global__ __launch_bounds__(256) void transpose_x_kernel(
    const float* __restrict__ x, unsigned short* __restrict__ xT)
{
  const int n0 = blockIdx.x * 64, c0 = blockIdx.y * 64, b = blockIdx.z;
  __shared__ __align__(16) unsigned short tx[64][72];   // [n][c]
  const int t = threadIdx.x;
  const int row = t >> 2;        // c index within tile
  const int seg = t & 3;         // 16 n each
  {
    const float* xp = x + ((size_t)(b * 256 + c0 + row)) * NSP + n0 + seg * 16;
    #pragma unroll
    for (int q4 = 0; q4 < 4; ++q4) {
      const float4 a = *reinterpret_cast<const float4*>(xp + q4 * 4);
      tx[seg * 16 + q4 * 4 + 0][row] = f2b(a.x);
      tx[seg * 16 + q4 * 4 + 1][row] = f2b(a.y);
      tx[seg * 16 + q4 * 4 + 2][row] = f2b(a.z);
      tx[seg * 16 + q4 * 4 + 3][row] = f2b(a.w);
    }
  }
  __syncthreads();
  const int nrow = t >> 2, ch = t & 3;
  unsigned short* op = xT + ((size_t)(b * NSP + n0 + nrow)) * 256 + c0 + ch * 16;
  *reinterpret_cast<float4*>(op)     = *reinterpret_cast<const float4*>(&tx[nrow][ch * 16]);
  *reinterpret_cast<float4*>(op + 8) = *reinterpret_cast<const float4*>(&tx[nrow][ch * 16 + 8]);
}

// ---------------- Kernel 1: MFMA qkv GEMM + BN + scatter ----------------
// C[co, n] = Wq[co, k] . X^T[n, k] ; even co-tile -> q/k (i-major), odd -> v (d-major)
__global__ __launch_bounds__(256) void qkv_gemm_kernel(
    const unsigned short* __restrict__ xT, const unsigned short* __restrict__ wqb,
    const float* __restrict__ gg, const float* __restrict__ bb,
    const float* __restrict__ mm, const float* __restrict__ vv,
    unsigned short* __restrict__ qb, unsigned short* __restrict__ kb,
    unsigned short* __restrict__ vb)
{
  const int n0 = blockIdx.x * 64;
  const int cotile = blockIdx.y;           // 8 tiles of 64 co
  const int b = blockIdx.z;
  const int co0 = cotile * 64;
  const int t = threadIdx.x;
  __shared__ __align__(16) unsigned short wt[64][136];   // [co][k-chunk 128]
  __shared__ __align__(16) unsigned short xt[64][136];   // [n][k-chunk 128]
  const int lane = t & 63, wave = t >> 6;
  const int m16 = lane & 15, quad = lane >> 4;
  const int row = t >> 2, seg = t & 3;

  f32x4 acc[4] = {};
  for (int kc = 0; kc < 2; ++kc) {
    if (kc) __syncthreads();
    {
      const unsigned short* wp = wqb + (size_t)(co0 + row) * 256 + kc * 128 + seg * 32;
      const unsigned short* xp = xT + ((size_t)(b * NSP + n0 + row)) * 256 + kc * 128 + seg * 32;
      #pragma unroll
      for (int u = 0; u < 4; ++u) {
        *reinterpret_cast<float4*>(&wt[row][seg * 32 + u * 8]) =
            *reinterpret_cast<const float4*>(wp + u * 8);
        *reinterpret_cast<float4*>(&xt[row][seg * 32 + u * 8]) =
            *reinterpret_cast<const float4*>(xp + u * 8);
      }
    }
    __syncthreads();
    if ((cotile & 1) == 0) {   // q/k: A = W (m=co), B = X (n=spatial)
      #pragma unroll
      for (int ks = 0; ks < 4; ++ks) {
        const short8 af = *reinterpret_cast<const short8*>(&wt[wave * 16 + m16][ks * 32 + quad * 8]);
        #pragma unroll
        for (int nt = 0; nt < 4; ++nt) {
          const short8 bf = *reinterpret_cast<const short8*>(&xt[nt * 16 + m16][ks * 32 + quad * 8]);
          acc[nt] = __builtin_amdgcn_mfma_f32_16x16x32_bf16(af, bf, acc[nt], 0, 0, 0);
        }
      }
    } else {                   // v: swapped -> A = X (m=spatial), B = W (n=co)
      #pragma unroll
      for (int ks = 0; ks < 4; ++ks) {
        const short8 bf = *reinterpret_cast<const short8*>(&wt[wave * 16 + m16][ks * 32 + quad * 8]);
        #pragma unroll
        for (int nt = 0; nt < 4; ++nt) {
          const short8 af = *reinterpret_cast<const short8*>(&xt[nt * 16 + m16][ks * 32 + quad * 8]);
          acc[nt] = __builtin_amdgcn_mfma_f32_16x16x32_bf16(af, bf, acc[nt], 0, 0, 0);
        }
      }
    }
  }

  const int head = cotile >> 1;
  const int bh = b * 4 + head;
  if ((cotile & 1) == 0) {
    // lane: n = n0 + nt*16 + m16 ; co = co0 + wave*16 + quad*4 + r
    const int coh = wave * 16 + quad * 4;   // 0..63 within head half (q if <32 else k)
    float sc[4], bi[4];
    #pragma unroll
    for (int r = 0; r < 4; ++r) {
      const int c = co0 + coh + r;
      sc[r] = gg[c] * rsqrtf(vv[c] + BEPS);
      bi[r] = bb[c] - mm[c] * sc[r];
    }
    unsigned short* dst = (coh < 32) ? qb : kb;
    const int d0 = coh & 31;
    #pragma unroll
    for (int nt = 0; nt < 4; ++nt) {
      const int i = n0 + nt * 16 + m16;
      uint2 pk2;
      pk2.x = pk_bf16(acc[nt][0] * sc[0] + bi[0], acc[nt][1] * sc[1] + bi[1]);
      pk2.y = pk_bf16(acc[nt][2] * sc[2] + bi[2], acc[nt][3] * sc[3] + bi[3]);
      *reinterpret_cast<uint2*>(dst + ((size_t)bh * NSP + i) * 32 + d0) = pk2;
    }
  } else {
    // lane: co = co0 + wave*16 + m16 (d = wave*16+m16) ; j = n0 + nt*16 + quad*4 + r
    const int c = co0 + wave * 16 + m16;
    const float sc = gg[c] * rsqrtf(vv[c] + BEPS);
    const float bi = bb[c] - mm[c] * sc;
    const int d = wave * 16 + m16;
    #pragma unroll
    for (int nt = 0; nt < 4; ++nt) {
      const int j = n0 + nt * 16 + quad * 4;
      uint2 pk2;
      pk2.x = pk_bf16(acc[nt][0] * sc + bi, acc[nt][1] * sc + bi);
      pk2.y = pk_bf16(acc[nt][2] * sc + bi, acc[nt][3] * sc + bi);
      *reinterpret_cast<uint2*>(vb + ((size_t)(bh * 64 + d)) * NSP + j) = pk2;
    }
  }
}

// ---------------- Kernel 2: MFMA flash attention, 128-i tiles, split over j ----------------
// Per block: 128 i x 1024 j for one (bh, split). Each wave owns 32 i (2 Q-frags).
// Fixed-max softmax, deferred l. Outputs unnormalized Opart (bf16) + lpart (f32).
__global__ __launch_bounds__(256, 3) void attn_kernel(
    const unsigned short* __restrict__ qb, const unsigned short* __restrict__ kb,
    const unsigned short* __restrict__ vb,
    unsigned short* __restrict__ Opart, float* __restrict__ lpart)
{
  const int i0    = blockIdx.x * 128;
  const int bh    = blockIdx.y;
  const int split = blockIdx.z;
  const int jbase = split * JCHUNK;
  const int t  = threadIdx.x;
  const int lane = t & 63, wave = t >> 6;
  const int m16 = lane & 15, quad = lane >> 4;
  __shared__ __align__(16) short qs[128][40];  // [i][d]
  __shared__ __align__(16) short ks[64][40];   // [j][d]
  __shared__ __align__(16) short vs[64][72];   // [d][j]
  __shared__ __align__(16) short ps[128][72];  // [i][j] bf16 P, wave-private rows

  {  // stage Q once: 128 rows x 32 bf16 (each thread 32B)
    const unsigned short* qp = qb + ((size_t)bh * NSP + i0) * 32;
    const int r = t >> 1, h = t & 1;
    *reinterpret_cast<float4*>(&qs[r][h * 16]) =
        *reinterpret_cast<const float4*>(qp + r * 32 + h * 16);
    *reinterpret_cast<float4*>(&qs[r][h * 16 + 8]) =
        *reinterpret_cast<const float4*>(qp + r * 32 + h * 16 + 8);
  }
  __syncthreads();
  short8 qfrag[2];
  qfrag[0] = *reinterpret_cast<const short8*>(&qs[wave * 32 + m16][quad * 8]);
  qfrag[1] = *reinterpret_cast<const short8*>(&qs[wave * 32 + 16 + m16][quad * 8]);

  float rsum[2] = {0.f, 0.f};
  f32x4 oacc[2][4] = {};

  const int srow = t >> 2, schunk = t & 3;
  for (int jt0 = 0; jt0 < JCHUNK; jt0 += 64) {
    const int j0 = jbase + jt0;
    __syncthreads();  // prev-iter ks/vs reads done before restaging
    {
      const unsigned short* kp = kb + ((size_t)bh * NSP + j0) * 32;
      *reinterpret_cast<float4*>(&ks[srow][schunk * 8]) =
          *reinterpret_cast<const float4*>(kp + srow * 32 + schunk * 8);
      const unsigned short* vp = vb + (size_t)bh * 64 * NSP + j0;
      *reinterpret_cast<float4*>(&vs[srow][schunk * 16]) =
          *reinterpret_cast<const float4*>(vp + (size_t)srow * NSP + schunk * 16);
      *reinterpret_cast<float4*>(&vs[srow][schunk * 16 + 8]) =
          *reinterpret_cast<const float4*>(vp + (size_t)srow * NSP + schunk * 16 + 8);
    }
    __syncthreads();

    // K fragments once, reused for both i-halves
    short8 kf[4];
    #pragma unroll
    for (int jt = 0; jt < 4; ++jt)
      kf[jt] = *reinterpret_cast<const short8*>(&ks[jt * 16 + m16][quad * 8]);

    #pragma unroll
    for (int it = 0; it < 2; ++it) {
      // S^T sub-tile: A = K (m=j), B = Q (n=i) -> lane holds i, rows j.
      f32x4 sacc[4];
      #pragma unroll
      for (int jt = 0; jt < 4; ++jt)
        sacc[jt] = __builtin_amdgcn_mfma_f32_16x16x32_bf16(kf[jt], qfrag[it],
                                                           (f32x4){0.f,0.f,0.f,0.f}, 0, 0, 0);
      const int irow = wave * 32 + it * 16 + m16;
      #pragma unroll
      for (int jt = 0; jt < 4; ++jt) {
        float p0 = __builtin_amdgcn_exp2f(sacc[jt][0] * SCALE_LOG2E);
        float p1 = __builtin_amdgcn_exp2f(sacc[jt][1] * SCALE_LOG2E);
        float p2 = __builtin_amdgcn_exp2f(sacc[jt][2] * SCALE_LOG2E);
        float p3 = __builtin_amdgcn_exp2f(sacc[jt][3] * SCALE_LOG2E);
        rsum[it] += (p0 + p1) + (p2 + p3);
        uint2 pk2;
        pk2.x = pk_bf16(p0, p1);
        pk2.y = pk_bf16(p2, p3);
        *reinterpret_cast<uint2*>(&ps[irow][jt * 16 + quad * 4]) = pk2;
      }
    }

    // PV: O[i][d] += P[i][j] V[j][d]; V-frags reused for both i-halves.
    short8 pa[2][2];
    #pragma unroll
    for (int it = 0; it < 2; ++it) {
      pa[it][0] = *reinterpret_cast<const short8*>(&ps[wave * 32 + it * 16 + m16][quad * 8]);
      pa[it][1] = *reinterpret_cast<const short8*>(&ps[wave * 32 + it * 16 + m16][32 + quad * 8]);
    }
    #pragma unroll
    for (int dt = 0; dt < 4; ++dt) {
      const short8 v0 = *reinterpret_cast<const short8*>(&vs[dt * 16 + m16][quad * 8]);
      const short8 v1 = *reinterpret_cast<const short8*>(&vs[dt * 16 + m16][32 + quad * 8]);
      #pragma unroll
      for (int it = 0; it < 2; ++it) {
        oacc[it][dt] = __builtin_amdgcn_mfma_f32_16x16x32_bf16(pa[it][0], v0, oacc[it][dt], 0, 0, 0);
        oacc[it][dt] = __builtin_amdgcn_mfma_f32_16x16x32_bf16(pa[it][1], v1, oacc[it][dt], 0, 0, 0);
      }
    }
  }

  // finalize l for this block's j-range: reduce across quads (same m16)
  #pragma unroll
  for (int it = 0; it < 2; ++it) {
    float rs = rsum[it];
    rs += __shfl_xor(rs, 16);
    rs += __shfl_xor(rs, 32);
    if (quad == 0)
      lpart[((size_t)split * 8 + bh) * NSP + i0 + wave * 32 + it * 16 + m16] = rs;
  }

  // store unnormalized O partial as bf16: [split][bh][d][i], 4 consecutive i -> 8B
  #pragma unroll
  for (int it = 0; it < 2; ++it)
    #pragma unroll
    for (int dt = 0; dt < 4; ++dt) {
      const int d = dt * 16 + m16;
      uint2 pk2;
      pk2.x = pk_bf16(oacc[it][dt][0], oacc[it][dt][1]);
      pk2.y = pk_bf16(oacc[it][dt][2], oacc[it][dt][3]);
      *reinterpret_cast<uint2*>(Opart +
          (((size_t)split * 8 + bh) * 64 + d) * NSP + i0 + wave * 32 + it * 16 + quad * 4) = pk2;
    }
}

// ---------------- Kernel 3: fused combine + pe -> yT (b, n, c) bf16 ----------------
__global__ __launch_bounds__(256) void fuse_kernel(
    const unsigned short* __restrict__ Opart, const float* __restrict__ lpart,
    const unsigned short* __restrict__ vb,
    const float* __restrict__ pw, const float* __restrict__ pg,
    const float* __restrict__ pb, const float* __restrict__ pm,
    const float* __restrict__ pv,
    unsigned short* __restrict__ yT)
{
  const int py = blockIdx.x;       // spatial row
  const int bh = blockIdx.y;       // 8
  const int b = bh >> 2, h = bh & 3;
  const int t = threadIdx.x;
  const int d = t >> 2, seg = t & 3;      // d 0..63 ; px window = seg*16..+15
  __shared__ float lsum[64];
  __shared__ __align__(16) unsigned short yt[64][72];   // [px][d]

  if (t < 64) {
    float ls = 0.f;
    #pragma unroll
    for (int s = 0; s < JSPLIT; ++s)
      ls += lpart[((size_t)s * 8 + bh) * NSP + py * 64 + t];
    lsum[t] = ls;
  }
  __syncthreads();

  const int c = h * 64 + d;
  const int i0 = py * 64 + seg * 16;
  float os[16] = {};
  #pragma unroll
  for (int s = 0; s < JSPLIT; ++s) {
    const unsigned short* op = Opart + (((size_t)s * 8 + bh) * 64 + d) * NSP + i0;
    #pragma unroll
    for (int u = 0; u < 16; ++u) os[u] += b2f(op[u]);
  }

  float w9[9];
  #pragma unroll
  for (int i = 0; i < 9; ++i) w9[i] = pw[c * 9 + i];
  const float sc = pg[c] * rsqrtf(pv[c] + BEPS);
  const float bi = pb[c] - pm[c] * sc;
  const unsigned short* vrow = vb + ((size_t)(bh * 64 + d)) * NSP;

  float conv[16] = {};
  #pragma unroll
  for (int dy = -1; dy <= 1; ++dy) {
    const int yy = py + dy;
    if (yy < 0 || yy > 63) continue;
    float vals[18];
    #pragma unroll
    for (int u = 0; u < 18; ++u) {
      const int px = seg * 16 - 1 + u;
      vals[u] = (px >= 0 && px < 64) ? b2f(vrow[yy * 64 + px]) : 0.f;
    }
    const float wr0 = w9[(dy + 1) * 3 + 0], wr1 = w9[(dy + 1) * 3 + 1], wr2 = w9[(dy + 1) * 3 + 2];
    #pragma unroll
    for (int u = 0; u < 16; ++u)
      conv[u] += vals[u] * wr0 + vals[u + 1] * wr1 + vals[u + 2] * wr2;
  }

  #pragma unroll
  for (int u = 0; u < 16; ++u) {
    const float yv = os[u] / lsum[seg * 16 + u] + conv[u] * sc + bi;
    yt[seg * 16 + u][d] = f2b(yv);
  }
  __syncthreads();

  const int prow = t >> 2, ch = t & 3;
  unsigned short* op = yT + ((size_t)(b * NSP + py * 64 + prow)) * 256 + h * 64 + ch * 16;
  *reinterpret_cast<float4*>(op)     = *reinterpret_cast<const float4*>(&yt[prow][ch * 16]);
  *reinterpret_cast<float4*>(op + 8) = *reinterpret_cast<const float4*>(&yt[prow][ch * 16 + 8]);
}

// ---------------- Kernel 4: MFMA proj GEMM + BN -> out f32 ----------------
// out[co, n] = BN(Wp[co,k] . yT[n,k]) ; swapped orientation: lane-fixed co, float4 along n
__global__ __launch_bounds__(256) void proj_gemm_kernel(
    const unsigned short* __restrict__ yT, const unsigned short* __restrict__ wpb,
    const float* __restrict__ gg, const float* __restrict__ bb,
    const float* __restrict__ mm, const float* __restrict__ vv,
    float* __restrict__ out)
{
  const int n0 = blockIdx.x * 64;
  const int co0 = blockIdx.y * 64;   // 4 tiles
  const int b = blockIdx.z;
  const int t = threadIdx.x;
  __shared__ __align__(16) unsigned short wt[64][136];
  __shared__ __align__(16) unsigned short yt[64][136];
  const int lane = t & 63, wave = t >> 6;
  const int m16 = lane & 15, quad = lane >> 4;
  const int row = t >> 2, seg = t & 3;

  f32x4 acc[4] = {};
  for (int kc = 0; kc < 2; ++kc) {
    if (kc) __syncthreads();
    {
      const unsigned short* wp = wpb + (size_t)(co0 + row) * 256 + kc * 128 + seg * 32;
      const unsigned short* yp = yT + ((size_t)(b * NSP + n0 + row)) * 256 + kc * 128 + seg * 32;
      #pragma unroll
      for (int u = 0; u < 4; ++u) {
        *reinterpret_cast<float4*>(&wt[row][seg * 32 + u * 8]) =
            *reinterpret_cast<const float4*>(wp + u * 8);
        *reinterpret_cast<float4*>(&yt[row][seg * 32 + u * 8]) =
            *reinterpret_cast<const float4*>(yp + u * 8);
      }
    }
    __syncthreads();
    #pragma unroll
    for (int ks = 0; ks < 4; ++ks) {
      const short8 bf = *reinterpret_cast<const short8*>(&wt[wave * 16 + m16][ks * 32 + quad * 8]);
      #pragma unroll
      for (int nt = 0; nt < 4; ++nt) {
        const short8 af = *reinterpret_cast<const short8*>(&yt[nt * 16 + m16][ks * 32 + quad * 8]);
        acc[nt] = __builtin_amdgcn_mfma_f32_16x16x32_bf16(af, bf, acc[nt], 0, 0, 0);
      }
    }
  }

  const int c = co0 + wave * 16 + m16;
  const float sc = gg[c] * rsqrtf(vv[c] + BEPS);
  const float bi = bb[c] - mm[c] * sc;
  #pragma unroll
  for (int nt = 0; nt < 4; ++nt) {
    const int n = n0 + nt * 16 + quad * 4;
    float4 ov;
    ov.x = acc[nt][0] * sc + bi; ov.y = acc[nt][1] * sc + bi;
    ov.z = acc[nt][2] * sc + bi; ov.w = acc[nt][3] * sc + bi;
    *reinterpret_cast<float4*>(out + ((size_t)(b * 256 + c)) * NSP + n) = ov;
  }
}

extern "C" void kernel_launch(void* const* d_in, const int* in_sizes, int n_in,
                              void* d_out, int out_size, void* d_ws, size_t ws_size,
                              hipStream_t stream)
{
  const float* x      = (const float*)d_in[0];
  const float* qkv_w  = (const float*)d_in[1];
  const float* qkv_g  = (const float*)d_in[2];
  const float* qkv_b  = (const float*)d_in[3];
  const float* qkv_m  = (const float*)d_in[4];
  const float* qkv_v  = (const float*)d_in[5];
  const float* proj_w = (const float*)d_in[6];
  const float* proj_g = (const float*)d_in[7];
  const float* proj_b = (const float*)d_in[8];
  const float* proj_m = (const float*)d_in[9];
  const float* proj_v = (const float*)d_in[10];
  const float* pe_w   = (const float*)d_in[11];
  const float* pe_g   = (const float*)d_in[12];
  const float* pe_b   = (const float*)d_in[13];
  const float* pe_m   = (const float*)d_in[14];
  const float* pe_v   = (const float*)d_in[15];
  float* out = (float*)d_out;

  unsigned short* qb = (unsigned short*)d_ws;             // 2MB
  unsigned short* kb = qb + (size_t)8 * NSP * 32;         // 2MB
  unsigned short* vb = kb + (size_t)8 * NSP * 32;         // 4MB
  unsigned short* Opart = vb + (size_t)8 * 64 * NSP;      // 16MB
  float* lpart = (float*)(Opart + (size_t)JSPLIT * 8 * 64 * NSP);  // 512KB
  unsigned short* xT = (unsigned short*)(lpart + (size_t)JSPLIT * 8 * NSP);  // 4MB
  unsigned short* yT = xT + (size_t)2 * NSP * 256;        // 4MB
  unsigned short* wqb = yT + (size_t)2 * NSP * 256;       // 256KB
  unsigned short* wpb = wqb + (size_t)512 * 256;          // 128KB

  cast_w_kernel<<<dim3(768), 256, 0, stream>>>(qkv_w, proj_w, wqb, wpb);
  transpose_x_kernel<<<dim3(64, 4, 2), 256, 0, stream>>>(x, xT);
  qkv_gemm_kernel<<<dim3(64, 8, 2), 256, 0, stream>>>(xT, wqb, qkv_g, qkv_b, qkv_m, qkv_v,
                                                      qb, kb, vb);
  attn_kernel<<<dim3(32, 8, JSPLIT), 256, 0, stream>>>(qb, kb, vb, Opart, lpart);
  fuse_kernel<<<dim3(64, 8), 256, 0, stream>>>(Opart, lpart, vb,
                                               pe_w, pe_g, pe_b, pe_m, pe_v, yT);
  proj_gemm_kernel<<<dim3(64, 4, 2), 256, 0, stream>>>(yT, wpb, proj_g, proj_b, proj_m, proj_v,
                                                       out);
}